// Round 4
// baseline (688.217 us; speedup 1.0000x reference)
//
#include <hip/hip_runtime.h>

typedef unsigned short ushort_t;
typedef short bf16x8 __attribute__((ext_vector_type(8)));
typedef float f32x4 __attribute__((ext_vector_type(4)));

#define S_LEN 4096
#define DIM   1536
#define NH    12
#define HD    128

__device__ __forceinline__ float bf2f(ushort_t h) {
  union { unsigned u; float f; } v; v.u = ((unsigned)h) << 16; return v.f;
}
__device__ __forceinline__ ushort_t f2bf(float f) {
  union { float f; unsigned u; } v; v.f = f;
  return (ushort_t)((v.u + 0x7FFFu + ((v.u >> 16) & 1u)) >> 16);
}

// async global->LDS, 16B per lane; LDS dest must be uniform base + lane*16
#define GLD16(gp, lp) __builtin_amdgcn_global_load_lds( \
    (const __attribute__((address_space(1))) unsigned int*)(gp), \
    (__attribute__((address_space(3))) unsigned int*)(lp), 16, 0, 0)

// ---------------------------------------------------------------- convert
__global__ void __launch_bounds__(256) cvt_bf16(const float* __restrict__ in,
                                                ushort_t* __restrict__ out, int n4) {
  int i = blockIdx.x * 256 + threadIdx.x;
  int stride = gridDim.x * 256;
  for (; i < n4; i += stride) {
    float4 v = ((const float4*)in)[i];
    ushort4 o;
    o.x = f2bf(v.x); o.y = f2bf(v.y); o.z = f2bf(v.z); o.w = f2bf(v.w);
    ((ushort4*)out)[i] = o;
  }
}

// ------------------------------------------------- GEMM: C = A * W^T + bias
// A [M][K] bf16, W [nz][N][K] bf16 (z = blockIdx.z), C [nz][M][N].
// F32OUT=0: C is bf16 (internal stages). F32OUT=1: C is fp32 (d_out contract:
// reference output dtype is float32 -- round-3 bug was writing bf16 here).
// 128x128 tile, BK=64, 4 waves each 64x64 (4x4 frags of 16x16x32).
// LDS linear [128][64] with chunk-XOR swizzle (chunk ^= row&7) applied on the
// global source address at staging and on the ds_read address (rule 21).
template <int F32OUT>
__global__ void __launch_bounds__(256) gemm_bt(
    const ushort_t* __restrict__ A, const ushort_t* __restrict__ Wbase,
    const float* __restrict__ b0, const float* __restrict__ b1, const float* __restrict__ b2,
    void* __restrict__ Cbase_v, int M, int N, int K)
{
  const int z = blockIdx.z;
  const ushort_t* W = Wbase + (size_t)z * N * K;
  const float* bias = (z == 0) ? b0 : (z == 1) ? b1 : b2;

  const int n0 = blockIdx.x * 128;
  const int m0 = blockIdx.y * 128;
  const int t = threadIdx.x;
  const int lane = t & 63;
  const int w = t >> 6;
  const int wr = w >> 1, wc = w & 1;
  const int mp = lane & 15, g = lane >> 4;

  __shared__ __attribute__((aligned(16))) ushort_t As[128 * 64];
  __shared__ __attribute__((aligned(16))) ushort_t Bs[128 * 64];

  f32x4 acc[4][4];
  f32x4 zero = {0.f, 0.f, 0.f, 0.f};
#pragma unroll
  for (int i = 0; i < 4; ++i)
#pragma unroll
    for (int j = 0; j < 4; ++j) acc[i][j] = zero;

  for (int kt = 0; kt < K; kt += 64) {
    __syncthreads();  // prior-iteration LDS reads done before overwrite
#pragma unroll
    for (int i = 0; i < 4; ++i) {
      int p = i * 256 + t;            // 1024 chunks of 16B per tile
      int r = p >> 3, sl = p & 7;
      int sg = sl ^ (r & 7);          // pre-swizzled global source
      GLD16(A + (size_t)(m0 + r) * K + kt + sg * 8, As + p * 8);
      GLD16(W + (size_t)(n0 + r) * K + kt + sg * 8, Bs + p * 8);
    }
    __syncthreads();  // staging visible (compiler drains vmcnt before barrier)
#pragma unroll
    for (int kk = 0; kk < 2; ++kk) {
      bf16x8 af[4], bfr[4];
#pragma unroll
      for (int mi = 0; mi < 4; ++mi) {
        int row = wr * 64 + mi * 16 + mp;
        int ch = (g + 4 * kk) ^ (row & 7);
        af[mi] = *(const bf16x8*)(As + row * 64 + ch * 8);
      }
#pragma unroll
      for (int ni = 0; ni < 4; ++ni) {
        int row = wc * 64 + ni * 16 + mp;
        int ch = (g + 4 * kk) ^ (row & 7);
        bfr[ni] = *(const bf16x8*)(Bs + row * 64 + ch * 8);
      }
#pragma unroll
      for (int mi = 0; mi < 4; ++mi)
#pragma unroll
        for (int ni = 0; ni < 4; ++ni)
          acc[mi][ni] = __builtin_amdgcn_mfma_f32_16x16x32_bf16(af[mi], bfr[ni], acc[mi][ni], 0, 0, 0);
    }
  }
#pragma unroll
  for (int ni = 0; ni < 4; ++ni) {
    int n = n0 + wc * 64 + ni * 16 + mp;
    float bv = bias[n];
#pragma unroll
    for (int mi = 0; mi < 4; ++mi) {
      int mbase = m0 + wr * 64 + mi * 16 + g * 4;   // C/D: row=(l>>4)*4+j, col=l&15
#pragma unroll
      for (int j = 0; j < 4; ++j) {
        if constexpr (F32OUT) {
          ((float*)Cbase_v)[(size_t)z * M * N + (size_t)(mbase + j) * N + n] =
              acc[mi][ni][j] + bv;
        } else {
          ((ushort_t*)Cbase_v)[(size_t)z * M * N + (size_t)(mbase + j) * N + n] =
              f2bf(acc[mi][ni][j] + bv);
        }
      }
    }
  }
}

// ------------------------------------- epilogue: RMSNorm + RoPE + relayout
__global__ void __launch_bounds__(256) epi_qkv(
    const ushort_t* __restrict__ raw,  // [3][S][DIM] bf16 (bias already added)
    const float* __restrict__ gq, const float* __restrict__ gk,
    const float* __restrict__ fcos, const float* __restrict__ fsin,
    ushort_t* __restrict__ Qh, ushort_t* __restrict__ Kh, ushort_t* __restrict__ Vh)
{
  const int s = blockIdx.x;
  const int t = threadIdx.x;
  const ushort_t* rq = raw + (size_t)s * DIM;
  const ushort_t* rk = raw + (size_t)S_LEN * DIM + (size_t)s * DIM;
  const ushort_t* rv = raw + 2 * (size_t)S_LEN * DIM + (size_t)s * DIM;

  float sq = 0.f, sk = 0.f;
#pragma unroll
  for (int i = 0; i < 6; ++i) {
    int e = t + 256 * i;
    float a = bf2f(rq[e]); sq += a * a;
    float b = bf2f(rk[e]); sk += b * b;
  }
  for (int off = 1; off < 64; off <<= 1) {
    sq += __shfl_xor(sq, off, 64);
    sk += __shfl_xor(sk, off, 64);
  }
  __shared__ float red[2][4];
  int w = t >> 6;
  if ((t & 63) == 0) { red[0][w] = sq; red[1][w] = sk; }
  __syncthreads();
  sq = red[0][0] + red[0][1] + red[0][2] + red[0][3];
  sk = red[1][0] + red[1][1] + red[1][2] + red[1][3];
  float invq = rsqrtf(sq * (1.f / 1536.f) + 1e-6f);
  float invk = rsqrtf(sk * (1.f / 1536.f) + 1e-6f);

  const float qscale = 0.08838834764831843f;  // 1/sqrt(128), folds score scale
#pragma unroll
  for (int i = 0; i < 3; ++i) {
    int p = t + 256 * i;               // 768 rotation pairs per row
    int hh = p >> 6, d = p & 63;
    int e1 = hh * 128 + d, e2 = e1 + 64;
    float c1 = fcos[s * 128 + d],      s1 = fsin[s * 128 + d];
    float c2 = fcos[s * 128 + d + 64], s2 = fsin[s * 128 + d + 64];
    float q1 = bf2f(rq[e1]) * invq * gq[e1];
    float q2 = bf2f(rq[e2]) * invq * gq[e2];
    float k1 = bf2f(rk[e1]) * invk * gk[e1];
    float k2 = bf2f(rk[e2]) * invk * gk[e2];
    size_t ob = ((size_t)hh * S_LEN + s) * 128;
    Qh[ob + d]      = f2bf((q1 * c1 - q2 * s1) * qscale);
    Qh[ob + d + 64] = f2bf((q2 * c2 + q1 * s2) * qscale);
    Kh[ob + d]      = f2bf(k1 * c1 - k2 * s1);
    Kh[ob + d + 64] = f2bf(k2 * c2 + k1 * s2);
  }
#pragma unroll
  for (int i = 0; i < 6; ++i) {
    int e = t + 256 * i;
    int hh = e >> 7, d = e & 127;
    Vh[((size_t)hh * S_LEN + s) * 128 + d] = rv[e];
  }
}

// ----------------------------------------------- V -> V^T per head (tiled)
__global__ void __launch_bounds__(256) transpose_v(const ushort_t* __restrict__ Vh,
                                                   ushort_t* __restrict__ VT) {
  const int st = blockIdx.x * 64;
  const int dt = blockIdx.y * 64;
  const int h = blockIdx.z;
  __shared__ ushort_t tile[64][65];
  const int t = threadIdx.x;
#pragma unroll
  for (int i = 0; i < 2; ++i) {
    int p = i * 256 + t;
    int r = p >> 3, c = (p & 7) * 8;
    bf16x8 v = *(const bf16x8*)(Vh + ((size_t)h * S_LEN + st + r) * 128 + dt + c);
#pragma unroll
    for (int j = 0; j < 8; ++j) tile[r][c + j] = ((ushort_t*)&v)[j];
  }
  __syncthreads();
#pragma unroll
  for (int i = 0; i < 2; ++i) {
    int p = i * 256 + t;
    int r = p >> 3, c = (p & 7) * 8;   // r: d-row, c: s chunk
    ushort_t tmp[8];
#pragma unroll
    for (int j = 0; j < 8; ++j) tmp[j] = tile[c + j][r];
    *(bf16x8*)(VT + ((size_t)h * 128 + dt + r) * S_LEN + st + c) = *(bf16x8*)tmp;
  }
}

// --------------------------------------------------------- flash attention
// block = 4 waves; wave w owns 16 Q rows; KV tiles of 64; online softmax.
__global__ void __launch_bounds__(256) attn(
    const ushort_t* __restrict__ Qh, const ushort_t* __restrict__ Kh,
    const ushort_t* __restrict__ VT, ushort_t* __restrict__ hb)
{
  const int qt = blockIdx.x;
  const int h = blockIdx.y;
  const int t = threadIdx.x;
  const int lane = t & 63;
  const int w = t >> 6;
  const int mp = lane & 15, g = lane >> 4;

  __shared__ __attribute__((aligned(16))) ushort_t Ks[64 * 128];
  __shared__ __attribute__((aligned(16))) ushort_t Vs[128 * 64];
  __shared__ __attribute__((aligned(16))) ushort_t Ps[4][16 * 64];

  const int q0 = qt * 64 + w * 16;
  bf16x8 qf[4];
#pragma unroll
  for (int ds = 0; ds < 4; ++ds)
    qf[ds] = *(const bf16x8*)(Qh + ((size_t)h * S_LEN + q0 + mp) * 128 + ds * 32 + g * 8);

  f32x4 zero = {0.f, 0.f, 0.f, 0.f};
  f32x4 oacc[8];
#pragma unroll
  for (int i = 0; i < 8; ++i) oacc[i] = zero;
  float mrun[4], lrun[4];
#pragma unroll
  for (int j = 0; j < 4; ++j) { mrun[j] = -1e30f; lrun[j] = 0.f; }

  const size_t kbase = (size_t)h * S_LEN * 128;
  const size_t vbase = (size_t)h * 128 * S_LEN;
  const float L2E = 1.4426950408889634f;

  for (int kv0 = 0; kv0 < S_LEN; kv0 += 64) {
    __syncthreads();  // prior-iteration LDS reads done
#pragma unroll
    for (int i = 0; i < 4; ++i) {      // K tile: 64 rows x 16 chunks
      int p = i * 256 + t;
      int r = p >> 4, sl = p & 15;
      int sg = sl ^ (r & 7);
      GLD16(Kh + kbase + (size_t)(kv0 + r) * 128 + sg * 8, Ks + p * 8);
    }
#pragma unroll
    for (int i = 0; i < 4; ++i) {      // V^T tile: 128 rows x 8 chunks
      int p = i * 256 + t;
      int r = p >> 3, sl = p & 7;
      int sg = sl ^ (r & 7);
      GLD16(VT + vbase + (size_t)r * S_LEN + kv0 + sg * 8, Vs + p * 8);
    }
    __syncthreads();

    // S = Q K^T  (16 x 64)
    f32x4 sacc[4];
#pragma unroll
    for (int nt = 0; nt < 4; ++nt) sacc[nt] = zero;
#pragma unroll
    for (int ds = 0; ds < 4; ++ds) {
#pragma unroll
      for (int nt = 0; nt < 4; ++nt) {
        int row = nt * 16 + mp;
        int ch = (g + 4 * ds) ^ (row & 7);
        bf16x8 kf = *(const bf16x8*)(Ks + row * 128 + ch * 8);
        sacc[nt] = __builtin_amdgcn_mfma_f32_16x16x32_bf16(qf[ds], kf, sacc[nt], 0, 0, 0);
      }
    }
    // online softmax: row r=4g+j lives in lanes 16g..16g+15, reg j
    float mx[4];
#pragma unroll
    for (int j = 0; j < 4; ++j)
      mx[j] = fmaxf(fmaxf(sacc[0][j], sacc[1][j]), fmaxf(sacc[2][j], sacc[3][j]));
    for (int off = 1; off < 16; off <<= 1)
#pragma unroll
      for (int j = 0; j < 4; ++j)
        mx[j] = fmaxf(mx[j], __shfl_xor(mx[j], off, 64));
    float scale[4], rowsum[4];
#pragma unroll
    for (int j = 0; j < 4; ++j) {
      float nm = fmaxf(mrun[j], mx[j]);
      scale[j] = exp2f((mrun[j] - nm) * L2E);
      mrun[j] = nm;
      rowsum[j] = 0.f;
    }
#pragma unroll
    for (int nt = 0; nt < 4; ++nt) {
#pragma unroll
      for (int j = 0; j < 4; ++j) {
        float p = exp2f((sacc[nt][j] - mrun[j]) * L2E);
        rowsum[j] += p;
        int row = g * 4 + j;
        int col = nt * 16 + mp;
        int ch = (col >> 3) ^ (row & 7);
        Ps[w][row * 64 + ch * 8 + (col & 7)] = f2bf(p);
      }
    }
    for (int off = 1; off < 16; off <<= 1)
#pragma unroll
      for (int j = 0; j < 4; ++j)
        rowsum[j] += __shfl_xor(rowsum[j], off, 64);
#pragma unroll
    for (int j = 0; j < 4; ++j)
      lrun[j] = lrun[j] * scale[j] + rowsum[j];
#pragma unroll
    for (int dt = 0; dt < 8; ++dt)
#pragma unroll
      for (int j = 0; j < 4; ++j)
        oacc[dt][j] *= scale[j];
    // O += P V   (A = P rows, B = V^T rows)
#pragma unroll
    for (int ks = 0; ks < 2; ++ks) {
      int ch = g + 4 * ks;
      bf16x8 pa = *(const bf16x8*)(Ps[w] + mp * 64 + ((ch ^ (mp & 7)) * 8));
#pragma unroll
      for (int dt = 0; dt < 8; ++dt) {
        int d = dt * 16 + mp;
        int vch = ch ^ (d & 7);
        bf16x8 vb = *(const bf16x8*)(Vs + d * 64 + vch * 8);
        oacc[dt] = __builtin_amdgcn_mfma_f32_16x16x32_bf16(pa, vb, oacc[dt], 0, 0, 0);
      }
    }
  }
#pragma unroll
  for (int j = 0; j < 4; ++j) {
    float inv = 1.f / lrun[j];
    int qrow = q0 + g * 4 + j;
#pragma unroll
    for (int dt = 0; dt < 8; ++dt) {
      int d = dt * 16 + mp;
      hb[(size_t)qrow * DIM + h * 128 + d] = f2bf(oacc[dt][j] * inv);
    }
  }
}

// ------------------------------------------------------------------ launch
extern "C" void kernel_launch(void* const* d_in, const int* in_sizes, int n_in,
                              void* d_out, int out_size, void* d_ws, size_t ws_size,
                              hipStream_t stream) {
  const float* x    = (const float*)d_in[0];
  const float* fcos = (const float*)d_in[1];
  const float* fsin = (const float*)d_in[2];
  const float* Wq   = (const float*)d_in[3];
  const float* bq   = (const float*)d_in[4];
  const float* Wk   = (const float*)d_in[5];
  const float* bk   = (const float*)d_in[6];
  const float* Wv   = (const float*)d_in[7];
  const float* bv   = (const float*)d_in[8];
  const float* Wo   = (const float*)d_in[9];
  const float* bo   = (const float*)d_in[10];
  const float* gq   = (const float*)d_in[11];
  const float* gk   = (const float*)d_in[12];

  char* ws = (char*)d_ws;
  ushort_t* xb  = (ushort_t*)(ws);              // [4096][1536]        12.6 MB
  ushort_t* wb  = (ushort_t*)(ws + 12582912);   // [4][1536][1536]     18.9 MB
  ushort_t* raw = (ushort_t*)(ws + 31457280);   // [3][4096][1536]     37.7 MB
  ushort_t* Qh  = (ushort_t*)(ws + 69206016);   // [12][4096][128]
  ushort_t* Kh  = (ushort_t*)(ws + 81788928);
  ushort_t* Vh  = (ushort_t*)(ws + 94371840);
  ushort_t* VT  = (ushort_t*)(ws + 106954752);  // [12][128][4096]
  ushort_t* hb  = (ushort_t*)(ws + 119537664);  // [4096][1536]  (end 132120576)

  cvt_bf16<<<2048, 256, 0, stream>>>(x,  xb,             6291456 / 4);
  cvt_bf16<<<2048, 256, 0, stream>>>(Wq, wb + 0 * 2359296, 2359296 / 4);
  cvt_bf16<<<2048, 256, 0, stream>>>(Wk, wb + 1 * 2359296, 2359296 / 4);
  cvt_bf16<<<2048, 256, 0, stream>>>(Wv, wb + 2 * 2359296, 2359296 / 4);
  cvt_bf16<<<2048, 256, 0, stream>>>(Wo, wb + 3 * 2359296, 2359296 / 4);

  gemm_bt<0><<<dim3(12, 32, 3), 256, 0, stream>>>(xb, wb, bq, bk, bv,
                                                  (void*)raw, 4096, 1536, 1536);
  epi_qkv<<<4096, 256, 0, stream>>>(raw, gq, gk, fcos, fsin, Qh, Kh, Vh);
  transpose_v<<<dim3(64, 2, 12), 256, 0, stream>>>(Vh, VT);
  attn<<<dim3(64, 12), 256, 0, stream>>>(Qh, Kh, VT, hb);
  gemm_bt<1><<<dim3(12, 32, 1), 256, 0, stream>>>(hb, wb + 3 * 2359296, bo, bo, bo,
                                                  (void*)d_out, 4096, 1536, 1536);
}

// Round 5
// 577.284 us; speedup vs baseline: 1.1922x; 1.1922x over previous
//
#include <hip/hip_runtime.h>

typedef unsigned short ushort_t;
typedef short bf16x8 __attribute__((ext_vector_type(8)));
typedef float f32x4 __attribute__((ext_vector_type(4)));
typedef float f32x16 __attribute__((ext_vector_type(16)));

#define S_LEN 4096
#define DIM   1536
#define NH    12
#define HD    128

__device__ __forceinline__ float bf2f(ushort_t h) {
  union { unsigned u; float f; } v; v.u = ((unsigned)h) << 16; return v.f;
}
__device__ __forceinline__ ushort_t f2bf(float f) {
  union { float f; unsigned u; } v; v.f = f;
  return (ushort_t)((v.u + 0x7FFFu + ((v.u >> 16) & 1u)) >> 16);
}
__device__ __forceinline__ unsigned cvtpk(float lo, float hi_) {  // 2xf32 -> packed bf16 (T12 recipe)
  unsigned r; asm("v_cvt_pk_bf16_f32 %0, %1, %2" : "=v"(r) : "v"(lo), "v"(hi_)); return r;
}

// async global->LDS, 16B per lane; LDS dest must be uniform base + lane*16
#define GLD16(gp, lp) __builtin_amdgcn_global_load_lds( \
    (const __attribute__((address_space(1))) unsigned int*)(gp), \
    (__attribute__((address_space(3))) unsigned int*)(lp), 16, 0, 0)

// ---------------------------------------------------------------- convert
__global__ void __launch_bounds__(256) cvt_bf16(const float* __restrict__ in,
                                                ushort_t* __restrict__ out, int n4) {
  int i = blockIdx.x * 256 + threadIdx.x;
  int stride = gridDim.x * 256;
  for (; i < n4; i += stride) {
    float4 v = ((const float4*)in)[i];
    ushort4 o;
    o.x = f2bf(v.x); o.y = f2bf(v.y); o.z = f2bf(v.z); o.w = f2bf(v.w);
    ((ushort4*)out)[i] = o;
  }
}

// ------------------------------------------------- GEMM: C = A * W^T + bias
// A [M][K] bf16, W [nz][N][K] bf16 (z = blockIdx.z), C [nz][M][N].
// F32OUT=1 for d_out (reference output dtype is float32).
template <int F32OUT>
__global__ void __launch_bounds__(256) gemm_bt(
    const ushort_t* __restrict__ A, const ushort_t* __restrict__ Wbase,
    const float* __restrict__ b0, const float* __restrict__ b1, const float* __restrict__ b2,
    void* __restrict__ Cbase_v, int M, int N, int K)
{
  const int z = blockIdx.z;
  const ushort_t* W = Wbase + (size_t)z * N * K;
  const float* bias = (z == 0) ? b0 : (z == 1) ? b1 : b2;

  const int n0 = blockIdx.x * 128;
  const int m0 = blockIdx.y * 128;
  const int t = threadIdx.x;
  const int lane = t & 63;
  const int w = t >> 6;
  const int wr = w >> 1, wc = w & 1;
  const int mp = lane & 15, g = lane >> 4;

  __shared__ __attribute__((aligned(16))) ushort_t As[128 * 64];
  __shared__ __attribute__((aligned(16))) ushort_t Bs[128 * 64];

  f32x4 acc[4][4];
  f32x4 zero = {0.f, 0.f, 0.f, 0.f};
#pragma unroll
  for (int i = 0; i < 4; ++i)
#pragma unroll
    for (int j = 0; j < 4; ++j) acc[i][j] = zero;

  for (int kt = 0; kt < K; kt += 64) {
    __syncthreads();
#pragma unroll
    for (int i = 0; i < 4; ++i) {
      int p = i * 256 + t;
      int r = p >> 3, sl = p & 7;
      int sg = sl ^ (r & 7);
      GLD16(A + (size_t)(m0 + r) * K + kt + sg * 8, As + p * 8);
      GLD16(W + (size_t)(n0 + r) * K + kt + sg * 8, Bs + p * 8);
    }
    __syncthreads();
#pragma unroll
    for (int kk = 0; kk < 2; ++kk) {
      bf16x8 af[4], bfr[4];
#pragma unroll
      for (int mi = 0; mi < 4; ++mi) {
        int row = wr * 64 + mi * 16 + mp;
        int ch = (g + 4 * kk) ^ (row & 7);
        af[mi] = *(const bf16x8*)(As + row * 64 + ch * 8);
      }
#pragma unroll
      for (int ni = 0; ni < 4; ++ni) {
        int row = wc * 64 + ni * 16 + mp;
        int ch = (g + 4 * kk) ^ (row & 7);
        bfr[ni] = *(const bf16x8*)(Bs + row * 64 + ch * 8);
      }
#pragma unroll
      for (int mi = 0; mi < 4; ++mi)
#pragma unroll
        for (int ni = 0; ni < 4; ++ni)
          acc[mi][ni] = __builtin_amdgcn_mfma_f32_16x16x32_bf16(af[mi], bfr[ni], acc[mi][ni], 0, 0, 0);
    }
  }
#pragma unroll
  for (int ni = 0; ni < 4; ++ni) {
    int n = n0 + wc * 64 + ni * 16 + mp;
    float bv = bias[n];
#pragma unroll
    for (int mi = 0; mi < 4; ++mi) {
      int mbase = m0 + wr * 64 + mi * 16 + g * 4;
#pragma unroll
      for (int j = 0; j < 4; ++j) {
        if constexpr (F32OUT) {
          ((float*)Cbase_v)[(size_t)z * M * N + (size_t)(mbase + j) * N + n] =
              acc[mi][ni][j] + bv;
        } else {
          ((ushort_t*)Cbase_v)[(size_t)z * M * N + (size_t)(mbase + j) * N + n] =
              f2bf(acc[mi][ni][j] + bv);
        }
      }
    }
  }
}

// ------------------------------------- epilogue: RMSNorm + RoPE + relayout
// Q is scaled by log2(e)/sqrt(128) so attn softmax works in base-2 domain.
__global__ void __launch_bounds__(256) epi_qkv(
    const ushort_t* __restrict__ raw,
    const float* __restrict__ gq, const float* __restrict__ gk,
    const float* __restrict__ fcos, const float* __restrict__ fsin,
    ushort_t* __restrict__ Qh, ushort_t* __restrict__ Kh, ushort_t* __restrict__ Vh)
{
  const int s = blockIdx.x;
  const int t = threadIdx.x;
  const ushort_t* rq = raw + (size_t)s * DIM;
  const ushort_t* rk = raw + (size_t)S_LEN * DIM + (size_t)s * DIM;
  const ushort_t* rv = raw + 2 * (size_t)S_LEN * DIM + (size_t)s * DIM;

  float sq = 0.f, sk = 0.f;
#pragma unroll
  for (int i = 0; i < 6; ++i) {
    int e = t + 256 * i;
    float a = bf2f(rq[e]); sq += a * a;
    float b = bf2f(rk[e]); sk += b * b;
  }
  for (int off = 1; off < 64; off <<= 1) {
    sq += __shfl_xor(sq, off, 64);
    sk += __shfl_xor(sk, off, 64);
  }
  __shared__ float red[2][4];
  int w = t >> 6;
  if ((t & 63) == 0) { red[0][w] = sq; red[1][w] = sk; }
  __syncthreads();
  sq = red[0][0] + red[0][1] + red[0][2] + red[0][3];
  sk = red[1][0] + red[1][1] + red[1][2] + red[1][3];
  float invq = rsqrtf(sq * (1.f / 1536.f) + 1e-6f);
  float invk = rsqrtf(sk * (1.f / 1536.f) + 1e-6f);

  const float qscale = 0.12752004708465604f;  // log2(e)/sqrt(128)
#pragma unroll
  for (int i = 0; i < 3; ++i) {
    int p = t + 256 * i;
    int hh = p >> 6, d = p & 63;
    int e1 = hh * 128 + d, e2 = e1 + 64;
    float c1 = fcos[s * 128 + d],      s1 = fsin[s * 128 + d];
    float c2 = fcos[s * 128 + d + 64], s2 = fsin[s * 128 + d + 64];
    float q1 = bf2f(rq[e1]) * invq * gq[e1];
    float q2 = bf2f(rq[e2]) * invq * gq[e2];
    float k1 = bf2f(rk[e1]) * invk * gk[e1];
    float k2 = bf2f(rk[e2]) * invk * gk[e2];
    size_t ob = ((size_t)hh * S_LEN + s) * 128;
    Qh[ob + d]      = f2bf((q1 * c1 - q2 * s1) * qscale);
    Qh[ob + d + 64] = f2bf((q2 * c2 + q1 * s2) * qscale);
    Kh[ob + d]      = f2bf(k1 * c1 - k2 * s1);
    Kh[ob + d + 64] = f2bf(k2 * c2 + k1 * s2);
  }
#pragma unroll
  for (int i = 0; i < 6; ++i) {
    int e = t + 256 * i;
    int hh = e >> 7, d = e & 127;
    Vh[((size_t)hh * S_LEN + s) * 128 + d] = rv[e];
  }
}

// ----------------------------------------------- V -> V^T per head (tiled)
__global__ void __launch_bounds__(256) transpose_v(const ushort_t* __restrict__ Vh,
                                                   ushort_t* __restrict__ VT) {
  const int st = blockIdx.x * 64;
  const int dt = blockIdx.y * 64;
  const int h = blockIdx.z;
  __shared__ ushort_t tile[64][65];
  const int t = threadIdx.x;
#pragma unroll
  for (int i = 0; i < 2; ++i) {
    int p = i * 256 + t;
    int r = p >> 3, c = (p & 7) * 8;
    bf16x8 v = *(const bf16x8*)(Vh + ((size_t)h * S_LEN + st + r) * 128 + dt + c);
#pragma unroll
    for (int j = 0; j < 8; ++j) tile[r][c + j] = ((ushort_t*)&v)[j];
  }
  __syncthreads();
#pragma unroll
  for (int i = 0; i < 2; ++i) {
    int p = i * 256 + t;
    int r = p >> 3, c = (p & 7) * 8;
    ushort_t tmp[8];
#pragma unroll
    for (int j = 0; j < 8; ++j) tmp[j] = tile[c + j][r];
    *(bf16x8*)(VT + ((size_t)h * 128 + dt + r) * S_LEN + st + c) = *(bf16x8*)tmp;
  }
}

// --------------------------------------------------------- flash attention
// 2 waves x 32 q-rows; swapped QK^T on 32x32x16 MFMA; in-register softmax;
// P->bf16 via cvt_pk + partner-lane (l^32) quad exchange; defer-max (THR=11,
// base-2 domain); XOR-swizzled K/V LDS tiles (G4).
__global__ void __launch_bounds__(128) attn32(
    const ushort_t* __restrict__ Qh, const ushort_t* __restrict__ Kh,
    const ushort_t* __restrict__ VT, ushort_t* __restrict__ hb)
{
  const int qt = blockIdx.x;
  const int h = blockIdx.y;
  const int t = threadIdx.x;
  const int lane = t & 63;
  const int w = t >> 6;
  const int ql = lane & 31;   // q within wave tile (and kv/d row selector)
  const int hi = lane >> 5;   // half-group

  __shared__ __attribute__((aligned(16))) ushort_t Ks[64 * 128]; // [kv][d], 16B-chunk ^= kv&7
  __shared__ __attribute__((aligned(16))) ushort_t Vs[128 * 64]; // [d][kv], 16B-chunk ^= d&7

  const int q0 = qt * 64 + w * 32;
  const size_t kbase = (size_t)h * S_LEN * 128;
  const size_t vbase = (size_t)h * 128 * S_LEN;

  // Q B-fragments: qf[s] = Q[q0+ql][16s + 8hi .. +7]  (resident, 32 VGPR)
  bf16x8 qf[8];
#pragma unroll
  for (int s = 0; s < 8; ++s)
    qf[s] = *(const bf16x8*)(Qh + ((size_t)h * S_LEN + q0 + ql) * 128 + 16 * s + 8 * hi);

  f32x16 oacc[4];
#pragma unroll
  for (int dt = 0; dt < 4; ++dt)
#pragma unroll
    for (int r = 0; r < 16; ++r) oacc[dt][r] = 0.f;
  float mrun = -1e30f, lrun = 0.f;

  for (int kv0 = 0; kv0 < S_LEN; kv0 += 64) {
    __syncthreads();
#pragma unroll
    for (int i = 0; i < 8; ++i) {      // K tile: 64 rows x 16 chunks
      int p = i * 128 + t;
      int r = p >> 4, sl = p & 15;
      int sg = sl ^ (r & 7);
      GLD16(Kh + kbase + (size_t)(kv0 + r) * 128 + sg * 8, Ks + p * 8);
    }
#pragma unroll
    for (int i = 0; i < 8; ++i) {      // V^T tile: 128 rows x 8 chunks
      int p = i * 128 + t;
      int r = p >> 3, sl = p & 7;
      int sg = sl ^ (r & 7);
      GLD16(VT + vbase + (size_t)r * S_LEN + kv0 + sg * 8, Vs + p * 8);
    }
    __syncthreads();

    // S^T = K . Q^T : lane holds 32 scores of q-column ql (16 per subtile)
    f32x16 sa0, sa1;
#pragma unroll
    for (int r = 0; r < 16; ++r) { sa0[r] = 0.f; sa1[r] = 0.f; }
    __builtin_amdgcn_s_setprio(1);
#pragma unroll
    for (int s = 0; s < 8; ++s) {
      int ck = (2 * s + hi) ^ (ql & 7);
      bf16x8 k0 = *(const bf16x8*)(Ks + ql * 128 + ck * 8);
      bf16x8 k1 = *(const bf16x8*)(Ks + (32 + ql) * 128 + ck * 8);
      sa0 = __builtin_amdgcn_mfma_f32_32x32x16_bf16(k0, qf[s], sa0, 0, 0, 0);
      sa1 = __builtin_amdgcn_mfma_f32_32x32x16_bf16(k1, qf[s], sa1, 0, 0, 0);
    }
    __builtin_amdgcn_s_setprio(0);

    // row max (tree) + partner exchange
    float mt[8];
#pragma unroll
    for (int r = 0; r < 8; ++r)
      mt[r] = fmaxf(fmaxf(sa0[r], sa0[r + 8]), fmaxf(sa1[r], sa1[r + 8]));
#pragma unroll
    for (int off = 4; off > 0; off >>= 1)
#pragma unroll
      for (int r = 0; r < 8; ++r)
        if (r < off) mt[r] = fmaxf(mt[r], mt[r + off]);
    float mx = fmaxf(mt[0], __shfl_xor(mt[0], 32));

    // defer-max: only rescale when max grew by > 11 (P bounded by 2^11)
    if (__any(mx - mrun > 11.0f)) {
      float nm = fmaxf(mrun, mx);
      float sc = exp2f(mrun - nm);
      mrun = nm;
      lrun *= sc;
#pragma unroll
      for (int dt = 0; dt < 4; ++dt)
#pragma unroll
        for (int r = 0; r < 16; ++r) oacc[dt][r] *= sc;
    }

    // P = exp2(S - mrun)  (log2e folded into Q), row sum (tree)
    float rt[8];
#pragma unroll
    for (int r = 0; r < 16; ++r) {
      sa0[r] = exp2f(sa0[r] - mrun);
      sa1[r] = exp2f(sa1[r] - mrun);
    }
#pragma unroll
    for (int r = 0; r < 8; ++r) rt[r] = (sa0[r] + sa0[r + 8]) + (sa1[r] + sa1[r + 8]);
#pragma unroll
    for (int off = 4; off > 0; off >>= 1)
#pragma unroll
      for (int r = 0; r < 8; ++r)
        if (r < off) rt[r] += rt[r + off];
    lrun += rt[0] + __shfl_xor(rt[0], 32);

    // pack P to bf16 words: quad a of subtile -> words [2a],[2a+1]
    unsigned pw0[8], pw1[8];
#pragma unroll
    for (int a = 0; a < 4; ++a) {
      pw0[2 * a]     = cvtpk(sa0[4 * a], sa0[4 * a + 1]);
      pw0[2 * a + 1] = cvtpk(sa0[4 * a + 2], sa0[4 * a + 3]);
      pw1[2 * a]     = cvtpk(sa1[4 * a], sa1[4 * a + 1]);
      pw1[2 * a + 1] = cvtpk(sa1[4 * a + 2], sa1[4 * a + 3]);
    }

    // O^T += V^T . P : per subtile st and k-step ks, exchange one quad with
    // partner lane (l^32): keep quad 2ks+hi, send quad 2ks+1-hi.
#pragma unroll
    for (int st = 0; st < 2; ++st) {
#pragma unroll
      for (int ks = 0; ks < 2; ++ks) {
        unsigned q0w0 = st ? pw1[4 * ks + 0] : pw0[4 * ks + 0];
        unsigned q0w1 = st ? pw1[4 * ks + 1] : pw0[4 * ks + 1];
        unsigned q1w0 = st ? pw1[4 * ks + 2] : pw0[4 * ks + 2];
        unsigned q1w1 = st ? pw1[4 * ks + 3] : pw0[4 * ks + 3];
        unsigned sw0 = hi ? q0w0 : q1w0;
        unsigned sw1 = hi ? q0w1 : q1w1;
        unsigned rv0 = (unsigned)__shfl_xor((int)sw0, 32);
        unsigned rv1 = (unsigned)__shfl_xor((int)sw1, 32);
        union { unsigned u[4]; bf16x8 v; } fw;
        fw.u[0] = hi ? rv0 : q0w0;
        fw.u[1] = hi ? rv1 : q0w1;
        fw.u[2] = hi ? q1w0 : rv0;
        fw.u[3] = hi ? q1w1 : rv1;
        __builtin_amdgcn_s_setprio(1);
#pragma unroll
        for (int dt = 0; dt < 4; ++dt) {
          int d = 32 * dt + ql;
          int cv = (4 * st + 2 * ks + hi) ^ (ql & 7);
          bf16x8 va = *(const bf16x8*)(Vs + d * 64 + cv * 8);
          oacc[dt] = __builtin_amdgcn_mfma_f32_32x32x16_bf16(va, fw.v, oacc[dt], 0, 0, 0);
        }
        __builtin_amdgcn_s_setprio(0);
      }
    }
  }

  // epilogue: lane owns q = q0+ql, d = 32dt + 8c + 4hi + m (m=0..3 per quad)
  float inv = 1.f / lrun;
#pragma unroll
  for (int dt = 0; dt < 4; ++dt) {
#pragma unroll
    for (int c = 0; c < 4; ++c) {
      float f0 = oacc[dt][4 * c + 0] * inv, f1 = oacc[dt][4 * c + 1] * inv;
      float f2 = oacc[dt][4 * c + 2] * inv, f3 = oacc[dt][4 * c + 3] * inv;
      uint2 u;
      u.x = cvtpk(f0, f1);
      u.y = cvtpk(f2, f3);
      *(uint2*)(hb + (size_t)(q0 + ql) * DIM + h * 128 + 32 * dt + 8 * c + 4 * hi) = u;
    }
  }
}

// ------------------------------------------------------------------ launch
extern "C" void kernel_launch(void* const* d_in, const int* in_sizes, int n_in,
                              void* d_out, int out_size, void* d_ws, size_t ws_size,
                              hipStream_t stream) {
  const float* x    = (const float*)d_in[0];
  const float* fcos = (const float*)d_in[1];
  const float* fsin = (const float*)d_in[2];
  const float* Wq   = (const float*)d_in[3];
  const float* bq   = (const float*)d_in[4];
  const float* Wk   = (const float*)d_in[5];
  const float* bk   = (const float*)d_in[6];
  const float* Wv   = (const float*)d_in[7];
  const float* bv   = (const float*)d_in[8];
  const float* Wo   = (const float*)d_in[9];
  const float* bo   = (const float*)d_in[10];
  const float* gq   = (const float*)d_in[11];
  const float* gk   = (const float*)d_in[12];

  char* ws = (char*)d_ws;
  ushort_t* xb  = (ushort_t*)(ws);              // [4096][1536]
  ushort_t* wb  = (ushort_t*)(ws + 12582912);   // [4][1536][1536]
  ushort_t* raw = (ushort_t*)(ws + 31457280);   // [3][4096][1536]
  ushort_t* Qh  = (ushort_t*)(ws + 69206016);   // [12][4096][128]
  ushort_t* Kh  = (ushort_t*)(ws + 81788928);
  ushort_t* Vh  = (ushort_t*)(ws + 94371840);
  ushort_t* VT  = (ushort_t*)(ws + 106954752);  // [12][128][4096]
  ushort_t* hb  = (ushort_t*)(ws + 119537664);  // [4096][1536]

  cvt_bf16<<<2048, 256, 0, stream>>>(x,  xb,             6291456 / 4);
  cvt_bf16<<<2048, 256, 0, stream>>>(Wq, wb + 0 * 2359296, 2359296 / 4);
  cvt_bf16<<<2048, 256, 0, stream>>>(Wk, wb + 1 * 2359296, 2359296 / 4);
  cvt_bf16<<<2048, 256, 0, stream>>>(Wv, wb + 2 * 2359296, 2359296 / 4);
  cvt_bf16<<<2048, 256, 0, stream>>>(Wo, wb + 3 * 2359296, 2359296 / 4);

  gemm_bt<0><<<dim3(12, 32, 3), 256, 0, stream>>>(xb, wb, bq, bk, bv,
                                                  (void*)raw, 4096, 1536, 1536);
  epi_qkv<<<4096, 256, 0, stream>>>(raw, gq, gk, fcos, fsin, Qh, Kh, Vh);
  transpose_v<<<dim3(64, 2, 12), 256, 0, stream>>>(Vh, VT);
  attn32<<<dim3(64, 12), 128, 0, stream>>>(Qh, Kh, VT, hb);
  gemm_bt<1><<<dim3(12, 32, 1), 256, 0, stream>>>(hb, wb + 3 * 2359296, bo, bo, bo,
                                                  (void*)d_out, 4096, 1536, 1536);
}

// Round 6
// 529.744 us; speedup vs baseline: 1.2991x; 1.0897x over previous
//
#include <hip/hip_runtime.h>

typedef unsigned short ushort_t;
typedef short bf16x8 __attribute__((ext_vector_type(8)));
typedef float f32x4 __attribute__((ext_vector_type(4)));
typedef float f32x16 __attribute__((ext_vector_type(16)));

#define S_LEN 4096
#define DIM   1536
#define NH    12
#define HD    128
#define KVSPLIT 4
#define ROWS (NH * S_LEN)          // 49152 (h*4096+q)
#define OPSPLIT_ELEMS ((size_t)ROWS * HD)  // 6291456 ushorts per split

__device__ __forceinline__ float bf2f(ushort_t h) {
  union { unsigned u; float f; } v; v.u = ((unsigned)h) << 16; return v.f;
}
__device__ __forceinline__ ushort_t f2bf(float f) {
  union { float f; unsigned u; } v; v.f = f;
  return (ushort_t)((v.u + 0x7FFFu + ((v.u >> 16) & 1u)) >> 16);
}
__device__ __forceinline__ unsigned cvtpk(float lo, float hi_) {
  unsigned r; asm("v_cvt_pk_bf16_f32 %0, %1, %2" : "=v"(r) : "v"(lo), "v"(hi_)); return r;
}

// async global->LDS, 16B per lane; LDS dest must be uniform base + lane*16
#define GLD16(gp, lp) __builtin_amdgcn_global_load_lds( \
    (const __attribute__((address_space(1))) unsigned int*)(gp), \
    (__attribute__((address_space(3))) unsigned int*)(lp), 16, 0, 0)

// ---------------------------------------------------------------- convert
__global__ void __launch_bounds__(256) cvt_bf16(const float* __restrict__ in,
                                                ushort_t* __restrict__ out, int n4) {
  int i = blockIdx.x * 256 + threadIdx.x;
  int stride = gridDim.x * 256;
  for (; i < n4; i += stride) {
    float4 v = ((const float4*)in)[i];
    ushort4 o;
    o.x = f2bf(v.x); o.y = f2bf(v.y); o.z = f2bf(v.z); o.w = f2bf(v.w);
    ((ushort4*)out)[i] = o;
  }
}

// ------------------------------------------------- GEMM: C = A * W^T + bias
template <int F32OUT>
__global__ void __launch_bounds__(256) gemm_bt(
    const ushort_t* __restrict__ A, const ushort_t* __restrict__ Wbase,
    const float* __restrict__ b0, const float* __restrict__ b1, const float* __restrict__ b2,
    void* __restrict__ Cbase_v, int M, int N, int K)
{
  const int z = blockIdx.z;
  const ushort_t* W = Wbase + (size_t)z * N * K;
  const float* bias = (z == 0) ? b0 : (z == 1) ? b1 : b2;

  const int n0 = blockIdx.x * 128;
  const int m0 = blockIdx.y * 128;
  const int t = threadIdx.x;
  const int lane = t & 63;
  const int w = t >> 6;
  const int wr = w >> 1, wc = w & 1;
  const int mp = lane & 15, g = lane >> 4;

  __shared__ __attribute__((aligned(16))) ushort_t As[128 * 64];
  __shared__ __attribute__((aligned(16))) ushort_t Bs[128 * 64];

  f32x4 acc[4][4];
  f32x4 zero = {0.f, 0.f, 0.f, 0.f};
#pragma unroll
  for (int i = 0; i < 4; ++i)
#pragma unroll
    for (int j = 0; j < 4; ++j) acc[i][j] = zero;

  for (int kt = 0; kt < K; kt += 64) {
    __syncthreads();
#pragma unroll
    for (int i = 0; i < 4; ++i) {
      int p = i * 256 + t;
      int r = p >> 3, sl = p & 7;
      int sg = sl ^ (r & 7);
      GLD16(A + (size_t)(m0 + r) * K + kt + sg * 8, As + p * 8);
      GLD16(W + (size_t)(n0 + r) * K + kt + sg * 8, Bs + p * 8);
    }
    __syncthreads();
#pragma unroll
    for (int kk = 0; kk < 2; ++kk) {
      bf16x8 af[4], bfr[4];
#pragma unroll
      for (int mi = 0; mi < 4; ++mi) {
        int row = wr * 64 + mi * 16 + mp;
        int ch = (g + 4 * kk) ^ (row & 7);
        af[mi] = *(const bf16x8*)(As + row * 64 + ch * 8);
      }
#pragma unroll
      for (int ni = 0; ni < 4; ++ni) {
        int row = wc * 64 + ni * 16 + mp;
        int ch = (g + 4 * kk) ^ (row & 7);
        bfr[ni] = *(const bf16x8*)(Bs + row * 64 + ch * 8);
      }
#pragma unroll
      for (int mi = 0; mi < 4; ++mi)
#pragma unroll
        for (int ni = 0; ni < 4; ++ni)
          acc[mi][ni] = __builtin_amdgcn_mfma_f32_16x16x32_bf16(af[mi], bfr[ni], acc[mi][ni], 0, 0, 0);
    }
  }
#pragma unroll
  for (int ni = 0; ni < 4; ++ni) {
    int n = n0 + wc * 64 + ni * 16 + mp;
    float bv = bias[n];
#pragma unroll
    for (int mi = 0; mi < 4; ++mi) {
      int mbase = m0 + wr * 64 + mi * 16 + g * 4;
#pragma unroll
      for (int j = 0; j < 4; ++j) {
        if constexpr (F32OUT) {
          ((float*)Cbase_v)[(size_t)z * M * N + (size_t)(mbase + j) * N + n] =
              acc[mi][ni][j] + bv;
        } else {
          ((ushort_t*)Cbase_v)[(size_t)z * M * N + (size_t)(mbase + j) * N + n] =
              f2bf(acc[mi][ni][j] + bv);
        }
      }
    }
  }
}

// ------------------------------------- epilogue: RMSNorm + RoPE + relayout
// Q is scaled by log2(e)/sqrt(128) so attn softmax works in base-2 domain.
__global__ void __launch_bounds__(256) epi_qkv(
    const ushort_t* __restrict__ raw,
    const float* __restrict__ gq, const float* __restrict__ gk,
    const float* __restrict__ fcos, const float* __restrict__ fsin,
    ushort_t* __restrict__ Qh, ushort_t* __restrict__ Kh, ushort_t* __restrict__ Vh)
{
  const int s = blockIdx.x;
  const int t = threadIdx.x;
  const ushort_t* rq = raw + (size_t)s * DIM;
  const ushort_t* rk = raw + (size_t)S_LEN * DIM + (size_t)s * DIM;
  const ushort_t* rv = raw + 2 * (size_t)S_LEN * DIM + (size_t)s * DIM;

  float sq = 0.f, sk = 0.f;
#pragma unroll
  for (int i = 0; i < 6; ++i) {
    int e = t + 256 * i;
    float a = bf2f(rq[e]); sq += a * a;
    float b = bf2f(rk[e]); sk += b * b;
  }
  for (int off = 1; off < 64; off <<= 1) {
    sq += __shfl_xor(sq, off, 64);
    sk += __shfl_xor(sk, off, 64);
  }
  __shared__ float red[2][4];
  int w = t >> 6;
  if ((t & 63) == 0) { red[0][w] = sq; red[1][w] = sk; }
  __syncthreads();
  sq = red[0][0] + red[0][1] + red[0][2] + red[0][3];
  sk = red[1][0] + red[1][1] + red[1][2] + red[1][3];
  float invq = rsqrtf(sq * (1.f / 1536.f) + 1e-6f);
  float invk = rsqrtf(sk * (1.f / 1536.f) + 1e-6f);

  const float qscale = 0.12752004708465604f;  // log2(e)/sqrt(128)
#pragma unroll
  for (int i = 0; i < 3; ++i) {
    int p = t + 256 * i;
    int hh = p >> 6, d = p & 63;
    int e1 = hh * 128 + d, e2 = e1 + 64;
    float c1 = fcos[s * 128 + d],      s1 = fsin[s * 128 + d];
    float c2 = fcos[s * 128 + d + 64], s2 = fsin[s * 128 + d + 64];
    float q1 = bf2f(rq[e1]) * invq * gq[e1];
    float q2 = bf2f(rq[e2]) * invq * gq[e2];
    float k1 = bf2f(rk[e1]) * invk * gk[e1];
    float k2 = bf2f(rk[e2]) * invk * gk[e2];
    size_t ob = ((size_t)hh * S_LEN + s) * 128;
    Qh[ob + d]      = f2bf((q1 * c1 - q2 * s1) * qscale);
    Qh[ob + d + 64] = f2bf((q2 * c2 + q1 * s2) * qscale);
    Kh[ob + d]      = f2bf(k1 * c1 - k2 * s1);
    Kh[ob + d + 64] = f2bf(k2 * c2 + k1 * s2);
  }
#pragma unroll
  for (int i = 0; i < 6; ++i) {
    int e = t + 256 * i;
    int hh = e >> 7, d = e & 127;
    Vh[((size_t)hh * S_LEN + s) * 128 + d] = rv[e];
  }
}

// ----------------------------------------------- V -> V^T per head (tiled)
__global__ void __launch_bounds__(256) transpose_v(const ushort_t* __restrict__ Vh,
                                                   ushort_t* __restrict__ VT) {
  const int st = blockIdx.x * 64;
  const int dt = blockIdx.y * 64;
  const int h = blockIdx.z;
  __shared__ ushort_t tile[64][65];
  const int t = threadIdx.x;
#pragma unroll
  for (int i = 0; i < 2; ++i) {
    int p = i * 256 + t;
    int r = p >> 3, c = (p & 7) * 8;
    bf16x8 v = *(const bf16x8*)(Vh + ((size_t)h * S_LEN + st + r) * 128 + dt + c);
#pragma unroll
    for (int j = 0; j < 8; ++j) tile[r][c + j] = ((ushort_t*)&v)[j];
  }
  __syncthreads();
#pragma unroll
  for (int i = 0; i < 2; ++i) {
    int p = i * 256 + t;
    int r = p >> 3, c = (p & 7) * 8;
    ushort_t tmp[8];
#pragma unroll
    for (int j = 0; j < 8; ++j) tmp[j] = tile[c + j][r];
    *(bf16x8*)(VT + ((size_t)h * 128 + dt + r) * S_LEN + st + c) = *(bf16x8*)tmp;
  }
}

// --------------------------------------------------------- flash attention
// KV-split flash: blockIdx.z = split (1024 KV positions = 16 tiles each).
// 2 waves x 32 q-rows; swapped QK^T on 32x32x16 MFMA; in-register softmax;
// P via cvt_pk + partner-lane quad exchange; defer-max; per-split normalized
// bf16 partial output + (m,l) for the combine pass.
__global__ void __launch_bounds__(128) attn32(
    const ushort_t* __restrict__ Qh, const ushort_t* __restrict__ Kh,
    const ushort_t* __restrict__ VT,
    ushort_t* __restrict__ opraw, ushort_t* __restrict__ opxb,
    float* __restrict__ mlbuf)
{
  const int qt = blockIdx.x;
  const int h = blockIdx.y;
  const int z = blockIdx.z;
  const int t = threadIdx.x;
  const int lane = t & 63;
  const int w = t >> 6;
  const int ql = lane & 31;
  const int hi = lane >> 5;

  __shared__ __attribute__((aligned(16))) ushort_t Ks[64 * 128];
  __shared__ __attribute__((aligned(16))) ushort_t Vs[128 * 64];

  const int q0 = qt * 64 + w * 32;
  const size_t kbase = (size_t)h * S_LEN * 128;
  const size_t vbase = (size_t)h * 128 * S_LEN;

  bf16x8 qf[8];
#pragma unroll
  for (int s = 0; s < 8; ++s)
    qf[s] = *(const bf16x8*)(Qh + ((size_t)h * S_LEN + q0 + ql) * 128 + 16 * s + 8 * hi);

  f32x16 oacc[4];
#pragma unroll
  for (int dt = 0; dt < 4; ++dt)
#pragma unroll
    for (int r = 0; r < 16; ++r) oacc[dt][r] = 0.f;
  float mrun = -1e30f, lrun = 0.f;

  const int kvbeg = z * (S_LEN / KVSPLIT);
  const int kvend = kvbeg + S_LEN / KVSPLIT;
  for (int kv0 = kvbeg; kv0 < kvend; kv0 += 64) {
    __syncthreads();
#pragma unroll
    for (int i = 0; i < 8; ++i) {      // K tile: 64 rows x 16 chunks
      int p = i * 128 + t;
      int r = p >> 4, sl = p & 15;
      int sg = sl ^ (r & 7);
      GLD16(Kh + kbase + (size_t)(kv0 + r) * 128 + sg * 8, Ks + p * 8);
    }
#pragma unroll
    for (int i = 0; i < 8; ++i) {      // V^T tile: 128 rows x 8 chunks
      int p = i * 128 + t;
      int r = p >> 3, sl = p & 7;
      int sg = sl ^ (r & 7);
      GLD16(VT + vbase + (size_t)r * S_LEN + kv0 + sg * 8, Vs + p * 8);
    }
    __syncthreads();

    // S^T = K . Q^T : lane holds 32 scores of q-column ql
    f32x16 sa0, sa1;
#pragma unroll
    for (int r = 0; r < 16; ++r) { sa0[r] = 0.f; sa1[r] = 0.f; }
    __builtin_amdgcn_s_setprio(1);
#pragma unroll
    for (int s = 0; s < 8; ++s) {
      int ck = (2 * s + hi) ^ (ql & 7);
      bf16x8 k0 = *(const bf16x8*)(Ks + ql * 128 + ck * 8);
      bf16x8 k1 = *(const bf16x8*)(Ks + (32 + ql) * 128 + ck * 8);
      sa0 = __builtin_amdgcn_mfma_f32_32x32x16_bf16(k0, qf[s], sa0, 0, 0, 0);
      sa1 = __builtin_amdgcn_mfma_f32_32x32x16_bf16(k1, qf[s], sa1, 0, 0, 0);
    }
    __builtin_amdgcn_s_setprio(0);

    float mt[8];
#pragma unroll
    for (int r = 0; r < 8; ++r)
      mt[r] = fmaxf(fmaxf(sa0[r], sa0[r + 8]), fmaxf(sa1[r], sa1[r + 8]));
#pragma unroll
    for (int off = 4; off > 0; off >>= 1)
#pragma unroll
      for (int r = 0; r < 8; ++r)
        if (r < off) mt[r] = fmaxf(mt[r], mt[r + off]);
    float mx = fmaxf(mt[0], __shfl_xor(mt[0], 32));

    if (__any(mx - mrun > 11.0f)) {
      float nm = fmaxf(mrun, mx);
      float sc = exp2f(mrun - nm);
      mrun = nm;
      lrun *= sc;
#pragma unroll
      for (int dt = 0; dt < 4; ++dt)
#pragma unroll
        for (int r = 0; r < 16; ++r) oacc[dt][r] *= sc;
    }

    float rt[8];
#pragma unroll
    for (int r = 0; r < 16; ++r) {
      sa0[r] = exp2f(sa0[r] - mrun);
      sa1[r] = exp2f(sa1[r] - mrun);
    }
#pragma unroll
    for (int r = 0; r < 8; ++r) rt[r] = (sa0[r] + sa0[r + 8]) + (sa1[r] + sa1[r + 8]);
#pragma unroll
    for (int off = 4; off > 0; off >>= 1)
#pragma unroll
      for (int r = 0; r < 8; ++r)
        if (r < off) rt[r] += rt[r + off];
    lrun += rt[0] + __shfl_xor(rt[0], 32);

    unsigned pw0[8], pw1[8];
#pragma unroll
    for (int a = 0; a < 4; ++a) {
      pw0[2 * a]     = cvtpk(sa0[4 * a], sa0[4 * a + 1]);
      pw0[2 * a + 1] = cvtpk(sa0[4 * a + 2], sa0[4 * a + 3]);
      pw1[2 * a]     = cvtpk(sa1[4 * a], sa1[4 * a + 1]);
      pw1[2 * a + 1] = cvtpk(sa1[4 * a + 2], sa1[4 * a + 3]);
    }

#pragma unroll
    for (int st = 0; st < 2; ++st) {
#pragma unroll
      for (int ks = 0; ks < 2; ++ks) {
        unsigned q0w0 = st ? pw1[4 * ks + 0] : pw0[4 * ks + 0];
        unsigned q0w1 = st ? pw1[4 * ks + 1] : pw0[4 * ks + 1];
        unsigned q1w0 = st ? pw1[4 * ks + 2] : pw0[4 * ks + 2];
        unsigned q1w1 = st ? pw1[4 * ks + 3] : pw0[4 * ks + 3];
        unsigned sw0 = hi ? q0w0 : q1w0;
        unsigned sw1 = hi ? q0w1 : q1w1;
        unsigned rv0 = (unsigned)__shfl_xor((int)sw0, 32);
        unsigned rv1 = (unsigned)__shfl_xor((int)sw1, 32);
        union { unsigned u[4]; bf16x8 v; } fw;
        fw.u[0] = hi ? rv0 : q0w0;
        fw.u[1] = hi ? rv1 : q0w1;
        fw.u[2] = hi ? q1w0 : rv0;
        fw.u[3] = hi ? q1w1 : rv1;
        __builtin_amdgcn_s_setprio(1);
#pragma unroll
        for (int dt = 0; dt < 4; ++dt) {
          int d = 32 * dt + ql;
          int cv = (4 * st + 2 * ks + hi) ^ (ql & 7);
          bf16x8 va = *(const bf16x8*)(Vs + d * 64 + cv * 8);
          oacc[dt] = __builtin_amdgcn_mfma_f32_32x32x16_bf16(va, fw.v, oacc[dt], 0, 0, 0);
        }
        __builtin_amdgcn_s_setprio(0);
      }
    }
  }

  // epilogue: per-split normalized bf16 partial + (m,l)
  ushort_t* Op = (z < 3) ? (opraw + (size_t)z * OPSPLIT_ELEMS) : opxb;
  const int row = h * S_LEN + q0 + ql;
  float inv = 1.f / lrun;
#pragma unroll
  for (int dt = 0; dt < 4; ++dt) {
#pragma unroll
    for (int c = 0; c < 4; ++c) {
      float f0 = oacc[dt][4 * c + 0] * inv, f1 = oacc[dt][4 * c + 1] * inv;
      float f2 = oacc[dt][4 * c + 2] * inv, f3 = oacc[dt][4 * c + 3] * inv;
      uint2 u;
      u.x = cvtpk(f0, f1);
      u.y = cvtpk(f2, f3);
      *(uint2*)(Op + (size_t)row * 128 + 32 * dt + 8 * c + 4 * hi) = u;
    }
  }
  if (hi == 0) {
    mlbuf[2 * ((size_t)z * ROWS + row)]     = mrun;
    mlbuf[2 * ((size_t)z * ROWS + row) + 1] = lrun;
  }
}

// ------------------------------------------------ combine KV-split partials
__global__ void __launch_bounds__(256) attn_combine(
    const ushort_t* __restrict__ opraw, const ushort_t* __restrict__ opxb,
    const float* __restrict__ mlbuf, ushort_t* __restrict__ hb)
{
  int gidx = blockIdx.x * 256 + threadIdx.x;   // 786432 = 49152 rows x 16 chunks
  int r = gidx >> 4;
  int c = gidx & 15;

  float m[KVSPLIT], l[KVSPLIT];
#pragma unroll
  for (int zz = 0; zz < KVSPLIT; ++zz) {
    m[zz] = mlbuf[2 * ((size_t)zz * ROWS + r)];
    l[zz] = mlbuf[2 * ((size_t)zz * ROWS + r) + 1];
  }
  float M = fmaxf(fmaxf(m[0], m[1]), fmaxf(m[2], m[3]));
  float wsum = 0.f, wz[KVSPLIT];
#pragma unroll
  for (int zz = 0; zz < KVSPLIT; ++zz) {
    wz[zz] = l[zz] * exp2f(m[zz] - M);
    wsum += wz[zz];
  }
  float invw = 1.f / wsum;

  float o[8];
#pragma unroll
  for (int j = 0; j < 8; ++j) o[j] = 0.f;
#pragma unroll
  for (int zz = 0; zz < KVSPLIT; ++zz) {
    const ushort_t* Op = (zz < 3) ? (opraw + (size_t)zz * OPSPLIT_ELEMS) : opxb;
    bf16x8 v = *(const bf16x8*)(Op + (size_t)r * 128 + c * 8);
#pragma unroll
    for (int j = 0; j < 8; ++j) o[j] += wz[zz] * bf2f((ushort_t)v[j]);
  }
  uint4 u;
  u.x = cvtpk(o[0] * invw, o[1] * invw);
  u.y = cvtpk(o[2] * invw, o[3] * invw);
  u.z = cvtpk(o[4] * invw, o[5] * invw);
  u.w = cvtpk(o[6] * invw, o[7] * invw);
  int q = r & (S_LEN - 1), h = r >> 12;
  *(uint4*)(hb + (size_t)q * DIM + h * 128 + c * 8) = u;
}

// ------------------------------------------------------------------ launch
extern "C" void kernel_launch(void* const* d_in, const int* in_sizes, int n_in,
                              void* d_out, int out_size, void* d_ws, size_t ws_size,
                              hipStream_t stream) {
  const float* x    = (const float*)d_in[0];
  const float* fcos = (const float*)d_in[1];
  const float* fsin = (const float*)d_in[2];
  const float* Wq   = (const float*)d_in[3];
  const float* bq   = (const float*)d_in[4];
  const float* Wk   = (const float*)d_in[5];
  const float* bk   = (const float*)d_in[6];
  const float* Wv   = (const float*)d_in[7];
  const float* bv   = (const float*)d_in[8];
  const float* Wo   = (const float*)d_in[9];
  const float* bo   = (const float*)d_in[10];
  const float* gq   = (const float*)d_in[11];
  const float* gk   = (const float*)d_in[12];

  char* ws = (char*)d_ws;
  ushort_t* xb  = (ushort_t*)(ws);              // [4096][1536]; reused as O-partial z=3
  ushort_t* wb  = (ushort_t*)(ws + 12582912);   // [4][1536][1536]
  ushort_t* raw = (ushort_t*)(ws + 31457280);   // [3][4096][1536]; reused as O-partial z=0..2
  ushort_t* Qh  = (ushort_t*)(ws + 69206016);   // [12][4096][128]
  ushort_t* Kh  = (ushort_t*)(ws + 81788928);
  ushort_t* Vh  = (ushort_t*)(ws + 94371840);   // reused as (m,l) buffer after transpose_v
  ushort_t* VT  = (ushort_t*)(ws + 106954752);  // [12][128][4096]
  ushort_t* hb  = (ushort_t*)(ws + 119537664);  // [4096][1536]

  cvt_bf16<<<2048, 256, 0, stream>>>(x,  xb,             6291456 / 4);
  cvt_bf16<<<2048, 256, 0, stream>>>(Wq, wb + 0 * 2359296, 2359296 / 4);
  cvt_bf16<<<2048, 256, 0, stream>>>(Wk, wb + 1 * 2359296, 2359296 / 4);
  cvt_bf16<<<2048, 256, 0, stream>>>(Wv, wb + 2 * 2359296, 2359296 / 4);
  cvt_bf16<<<2048, 256, 0, stream>>>(Wo, wb + 3 * 2359296, 2359296 / 4);

  gemm_bt<0><<<dim3(12, 32, 3), 256, 0, stream>>>(xb, wb, bq, bk, bv,
                                                  (void*)raw, 4096, 1536, 1536);
  epi_qkv<<<4096, 256, 0, stream>>>(raw, gq, gk, fcos, fsin, Qh, Kh, Vh);
  transpose_v<<<dim3(64, 2, 12), 256, 0, stream>>>(Vh, VT);
  attn32<<<dim3(64, 12, KVSPLIT), 128, 0, stream>>>(Qh, Kh, VT, raw, xb, (float*)Vh);
  attn_combine<<<3072, 256, 0, stream>>>(raw, xb, (const float*)Vh, hb);
  gemm_bt<1><<<dim3(12, 32, 1), 256, 0, stream>>>(hb, wb + 3 * 2359296, bo, bo, bo,
                                                  (void*)d_out, 4096, 1536, 1536);
}